// Round 11
// baseline (324.678 us; speedup 1.0000x reference)
//
#include <hip/hip_runtime.h>
#include <math.h>

#define DIM 4096
#define NH 32
#define NKV 8
#define HD 128
#define WINDOW 4096
#define BATCH 32
#define QKV_N 6144
#define ATTN_SCALE 0.08838834764831845f
#define WCHUNK 128
#define NCW 32         // WINDOW / WCHUNK
#define SLICES 32      // GEMM K-split, kn = 128

__device__ __forceinline__ float4 f4max(float4 a, float4 b) {
  return make_float4(fmaxf(a.x, b.x), fmaxf(a.y, b.y), fmaxf(a.z, b.z), fmaxf(a.w, b.w));
}
__device__ __forceinline__ float4 f4add(float4 a, float4 b) {
  return make_float4(a.x + b.x, a.y + b.y, a.z + b.z, a.w + b.w);
}
__device__ __forceinline__ void fma4(float4& a, float4 x, float4 y) {
  a.x = fmaf(x.x, y.x, a.x); a.y = fmaf(x.y, y.y, a.y);
  a.z = fmaf(x.z, y.z, a.z); a.w = fmaf(x.w, y.w, a.w);
}
__device__ __forceinline__ void fma4s(float4& a, float s, float4 v) {
  a.x = fmaf(s, v.x, a.x); a.y = fmaf(s, v.y, a.y);
  a.z = fmaf(s, v.z, a.z); a.w = fmaf(s, v.w, a.w);
}
__device__ __forceinline__ float4 wred_max(float4 v) {
#pragma unroll
  for (int o = 1; o < 64; o <<= 1) {
    v.x = fmaxf(v.x, __shfl_xor(v.x, o));
    v.y = fmaxf(v.y, __shfl_xor(v.y, o));
    v.z = fmaxf(v.z, __shfl_xor(v.z, o));
    v.w = fmaxf(v.w, __shfl_xor(v.w, o));
  }
  return v;
}
__device__ __forceinline__ float4 wred_add(float4 v) {
#pragma unroll
  for (int o = 1; o < 64; o <<= 1) {
    v.x += __shfl_xor(v.x, o);
    v.y += __shfl_xor(v.y, o);
    v.z += __shfl_xor(v.z, o);
    v.w += __shfl_xor(v.w, o);
  }
  return v;
}

// ---------------------------------------------------------------------------
// GEMM partials v3 (round-9 proven): wave tile = 256 cols x 4 rows x 128 k.
// blockIdx = strip (fastest) + rowhalf*nstrip + slice*2*nstrip; row-half pairs
// sit nstrip (=0 mod 8) apart -> same XCD L2 serves the shared w-tile.
// Lane l -> 4 consecutive cols: each wave w-load = 1 KB contiguous unique.
// part[(slice*32 + r)*N + c] = sum_{k in slice} x[r][k] * w[k][c]
// ---------------------------------------------------------------------------
template<int N>
__global__ __launch_bounds__(256, 4)
void k_gemm(const float* __restrict__ x, const float* __restrict__ w,
            float* __restrict__ part, int nstrip) {
  const int bid = blockIdx.x;
  const int strip = bid % nstrip;
  const int rh = (bid / nstrip) & 1;
  const int slice = bid / (nstrip * 2);
  const int t = threadIdx.x;
  const int l = t & 63;
  const int r0 = rh * 16 + (t >> 6) * 4;   // 4 rows per thread
  const int ks = slice * 128;
  const int c0 = strip * 256;

  float4 acc[4];
#pragma unroll
  for (int i = 0; i < 4; ++i) acc[i] = make_float4(0.f, 0.f, 0.f, 0.f);

  const float* wp = w + (size_t)ks * N + c0 + 4 * l;
  const float* xp = x + (size_t)r0 * DIM + ks;

  for (int k4 = 0; k4 < 32; ++k4) {
    float4 xr[4];
#pragma unroll
    for (int r = 0; r < 4; ++r)
      xr[r] = *(const float4*)(xp + (size_t)r * DIM + 4 * k4);
#pragma unroll
    for (int kk = 0; kk < 4; ++kk) {
      float4 wv = *(const float4*)wp;
      wp += N;
#pragma unroll
      for (int r = 0; r < 4; ++r) {
        float xs = (kk == 0) ? xr[r].x : (kk == 1) ? xr[r].y : (kk == 2) ? xr[r].z : xr[r].w;
        fma4s(acc[r], xs, wv);
      }
    }
  }
  float* p = part + ((size_t)slice * 32 + r0) * N + c0 + 4 * l;
#pragma unroll
  for (int i = 0; i < 4; ++i) *(float4*)(p + (size_t)i * N) = acc[i];
}

// ---------------------------------------------------------------------------
// Slice-reduce qkv partials + RoPE, scatter q / knew / vnew.
// ---------------------------------------------------------------------------
__global__ __launch_bounds__(256)
void k_rope(const float* __restrict__ part, const float* __restrict__ cosv,
            const float* __restrict__ sinv, float* __restrict__ q,
            float* __restrict__ knew, float* __restrict__ vnew) {
  int idx = blockIdx.x * 256 + threadIdx.x;   // < 32*48*64 = 98304
  int r = idx / 3072;
  int rem = idx - r * 3072;
  int head = rem >> 6;
  int d = rem & 63;
  int c1 = head * 128 + d;
  int c2 = c1 + 64;
  float v1 = 0.f, v2 = 0.f;
#pragma unroll 8
  for (int s = 0; s < SLICES; ++s) {
    v1 += part[((size_t)s * 32 + r) * QKV_N + c1];
    v2 += part[((size_t)s * 32 + r) * QKV_N + c2];
  }
  if (head < NH + NKV) {
    float c_lo = cosv[d], c_hi = cosv[d + 64];
    float s_lo = sinv[d], s_hi = sinv[d + 64];
    float o1 = v1 * c_lo - v2 * s_lo;
    float o2 = v2 * c_hi + v1 * s_hi;
    if (head < NH) {
      q[((size_t)r * NH + head) * HD + d] = o1;
      q[((size_t)r * NH + head) * HD + d + 64] = o2;
    } else {
      int g = head - NH;
      knew[((size_t)r * NKV + g) * HD + d] = o1;
      knew[((size_t)r * NKV + g) * HD + d + 64] = o2;
    }
  } else {
    int g = head - NH - NKV;
    vnew[((size_t)r * NKV + g) * HD + d] = v1;
    vnew[((size_t)r * NKV + g) * HD + d + 64] = v2;
  }
}

// ---------------------------------------------------------------------------
// Flash-decode: each wave owns one 128-position chunk of one (b,g).
// grid 2048 x 256thr (4 waves); ~100 VGPR -> ~5 blocks/CU resident
// (20 waves/CU, +25% vs round-9's 16). Wave-private LDS, no __syncthreads.
// ---------------------------------------------------------------------------
__global__ __launch_bounds__(256, 4)
void k_attn(const float* __restrict__ q, const float* __restrict__ knew,
            const float* __restrict__ vnew, const float* __restrict__ cache_k,
            const float* __restrict__ cache_v, const float* __restrict__ mask,
            const int* __restrict__ start_pos_p,
            float* __restrict__ pvp, float* __restrict__ msp) {
  __shared__ __align__(16) float q_s_all[4][4 * HD];        // 8 KB
  __shared__ __align__(16) float s_s_all[4][WCHUNK * 4];    // 8 KB
  const int t = threadIdx.x;
  const int w = t >> 6, lane = t & 63;
  float* q_s = q_s_all[w];
  float* s_s = s_s_all[w];
  const int gw = blockIdx.x * 4 + w;    // 0..8191
  const int bg = gw & 255;
  const int c = gw >> 8;                // 0..31
  const int b = bg >> 3;
  const int sp = start_pos_p[0];
  const int cur = sp & (WINDOW - 1);
  int plen = ((sp + 1 + 31) >> 5) << 5;
  if (plen > WINDOW) plen = WINDOW;
  const int t0 = c * WCHUNK;
  const int tend = min(t0 + WCHUNK, plen);

  const size_t pidx = ((size_t)c * 256 + bg) * 4;
  float* pvb = pvp + pidx * HD;
  float* msb = msp + pidx * 2;

  if (t0 >= plen) {
    if (lane < 8) msb[lane] = (lane & 1) ? 0.f : -1e30f;
    for (int i = lane; i < 4 * HD; i += 64) pvb[i] = 0.f;
    return;
  }

  // wave-local q load (4 heads x 128 contiguous)
  {
    const float* qsrc = q + ((size_t)b * NH + (bg & 7) * 4) * HD;
    *(float4*)(&q_s[lane * 8]) = *(const float4*)(qsrc + lane * 8);
    *(float4*)(&q_s[lane * 8 + 4]) = *(const float4*)(qsrc + lane * 8 + 4);
  }

  const float* kbase = cache_k + (size_t)bg * WINDOW * HD;
  const float* vbase = cache_v + (size_t)bg * WINDOW * HD;
  const float* krow_new = knew + (size_t)bg * HD;
  const float* vrow_new = vnew + (size_t)bg * HD;

  // ---- Phase 1: scores; 16 row-lanes x 8 iters; batch 8 loads/row ----
  {
    const int p0 = lane >> 2;   // 0..15
    const int dl = lane & 3;
    for (int tt = t0 + p0; tt < t0 + WCHUNK; tt += 16) {
      if (tt < tend) {
        const float* krow = (tt == cur) ? krow_new : (kbase + (size_t)tt * HD);
        float4 kreg[8];
#pragma unroll
        for (int j = 0; j < 8; ++j)
          kreg[j] = *(const float4*)(krow + 4 * (dl + 4 * j));
        float4 a0 = {0,0,0,0}, a1 = {0,0,0,0}, a2 = {0,0,0,0}, a3 = {0,0,0,0};
#pragma unroll
        for (int j = 0; j < 8; ++j) {
          const int f = dl + 4 * j;
          fma4(a0, kreg[j], *(const float4*)(&q_s[0 * HD + 4 * f]));
          fma4(a1, kreg[j], *(const float4*)(&q_s[1 * HD + 4 * f]));
          fma4(a2, kreg[j], *(const float4*)(&q_s[2 * HD + 4 * f]));
          fma4(a3, kreg[j], *(const float4*)(&q_s[3 * HD + 4 * f]));
        }
        float s0 = a0.x + a0.y + a0.z + a0.w;
        float s1 = a1.x + a1.y + a1.z + a1.w;
        float s2 = a2.x + a2.y + a2.z + a2.w;
        float s3 = a3.x + a3.y + a3.z + a3.w;
        s0 += __shfl_xor(s0, 1); s0 += __shfl_xor(s0, 2);
        s1 += __shfl_xor(s1, 1); s1 += __shfl_xor(s1, 2);
        s2 += __shfl_xor(s2, 1); s2 += __shfl_xor(s2, 2);
        s3 += __shfl_xor(s3, 1); s3 += __shfl_xor(s3, 2);
        float sv = (dl == 0) ? s0 : (dl == 1) ? s1 : (dl == 2) ? s2 : s3;
        s_s[(tt - t0) * 4 + dl] = sv * ATTN_SCALE + mask[(size_t)b * WINDOW + tt];
      } else {
        s_s[(tt - t0) * 4 + dl] = -1e30f;
      }
    }
  }

  // ---- Phase 2: wave softmax over 128 rows (2 rows/lane) ----
  float4 sa = *(const float4*)(&s_s[lane * 4]);
  float4 sb = *(const float4*)(&s_s[(lane + 64) * 4]);
  float4 mx = wred_max(f4max(sa, sb));
  float4 e0, e1;
  e0.x = __expf(sa.x - mx.x); e0.y = __expf(sa.y - mx.y);
  e0.z = __expf(sa.z - mx.z); e0.w = __expf(sa.w - mx.w);
  e1.x = __expf(sb.x - mx.x); e1.y = __expf(sb.y - mx.y);
  e1.z = __expf(sb.z - mx.z); e1.w = __expf(sb.w - mx.w);
  *(float4*)(&s_s[lane * 4]) = e0;
  *(float4*)(&s_s[(lane + 64) * 4]) = e1;
  float4 sm = wred_add(f4add(e0, e1));
  if (lane == 0) {
    msb[0] = mx.x; msb[1] = sm.x;
    msb[2] = mx.y; msb[3] = sm.y;
    msb[4] = mx.z; msb[5] = sm.z;
    msb[6] = mx.w; msb[7] = sm.w;
  }

  // ---- Phase 3: PV; half-wave owns even/odd rows; unroll for MLP ----
  {
    const int d4 = lane & 31;
    const int half = lane >> 5;
    float4 a0 = {0,0,0,0}, a1 = {0,0,0,0}, a2 = {0,0,0,0}, a3 = {0,0,0,0};
#pragma unroll 4
    for (int tt = t0 + half; tt < tend; tt += 2) {
      const float* vrow = (tt == cur) ? vrow_new : (vbase + (size_t)tt * HD);
      float4 vv = *(const float4*)(vrow + 4 * d4);
      float4 p = *(const float4*)(&s_s[(tt - t0) * 4]);
      fma4s(a0, p.x, vv);
      fma4s(a1, p.y, vv);
      fma4s(a2, p.z, vv);
      fma4s(a3, p.w, vv);
    }
    a0.x += __shfl_xor(a0.x, 32); a0.y += __shfl_xor(a0.y, 32);
    a0.z += __shfl_xor(a0.z, 32); a0.w += __shfl_xor(a0.w, 32);
    a1.x += __shfl_xor(a1.x, 32); a1.y += __shfl_xor(a1.y, 32);
    a1.z += __shfl_xor(a1.z, 32); a1.w += __shfl_xor(a1.w, 32);
    a2.x += __shfl_xor(a2.x, 32); a2.y += __shfl_xor(a2.y, 32);
    a2.z += __shfl_xor(a2.z, 32); a2.w += __shfl_xor(a2.w, 32);
    a3.x += __shfl_xor(a3.x, 32); a3.y += __shfl_xor(a3.y, 32);
    a3.z += __shfl_xor(a3.z, 32); a3.w += __shfl_xor(a3.w, 32);
    if (half == 0) {
      *(float4*)(&pvb[0 * HD + 4 * d4]) = a0;
      *(float4*)(&pvb[1 * HD + 4 * d4]) = a1;
      *(float4*)(&pvb[2 * HD + 4 * d4]) = a2;
      *(float4*)(&pvb[3 * HD + 4 * d4]) = a3;
    }
  }
}

// ---------------------------------------------------------------------------
// Combine chunk partials: online LSE merge over NCW chunks.
// ---------------------------------------------------------------------------
__global__ __launch_bounds__(256)
void k_combine(const float* __restrict__ pvp, const float* __restrict__ msp,
               float* __restrict__ attn_out) {
  int idx = blockIdx.x * 256 + threadIdx.x;   // < 32*4096
  int b = idx >> 12;
  int rem = idx & 4095;
  int hf = rem >> 7;
  int d = rem & 127;
  int g = hf >> 2, hh = hf & 3;
  int bg = b * 8 + g;
  float M = -1e30f, den = 0.f, num = 0.f;
#pragma unroll 4
  for (int c = 0; c < NCW; ++c) {
    size_t base = ((size_t)c * 256 + bg) * 4 + hh;
    float m = msp[base * 2];
    float s = msp[base * 2 + 1];
    float p = pvp[base * HD + d];
    float Mn = fmaxf(M, m);
    float so = __expf(M - Mn);
    float sn = __expf(m - Mn);
    den = den * so + s * sn;
    num = num * so + p * sn;
    M = Mn;
  }
  attn_out[idx] = num / den;
}

// ---------------------------------------------------------------------------
// Reduce wo partials -> out.
// ---------------------------------------------------------------------------
__global__ __launch_bounds__(256)
void k_reduce(const float* __restrict__ part, float* __restrict__ out) {
  int idx = blockIdx.x * 256 + threadIdx.x;   // < 32*4096
  float s = 0.f;
#pragma unroll 8
  for (int sl = 0; sl < SLICES; ++sl) s += part[(size_t)sl * BATCH * DIM + idx];
  out[idx] = s;
}

extern "C" void kernel_launch(void* const* d_in, const int* in_sizes, int n_in,
                              void* d_out, int out_size, void* d_ws, size_t ws_size,
                              hipStream_t stream) {
  const float* x       = (const float*)d_in[0];
  const float* wqkv    = (const float*)d_in[1];
  const float* wo      = (const float*)d_in[2];
  const float* cosv    = (const float*)d_in[3];
  const float* sinv    = (const float*)d_in[4];
  const float* cache_k = (const float*)d_in[5];
  const float* cache_v = (const float*)d_in[6];
  const float* mask    = (const float*)d_in[7];
  const int*   start_p = (const int*)d_in[8];
  float* ws = (float*)d_ws;

  float* partA    = ws;                        // 32*32*6144 = 6,291,456
  float* q        = ws + 6291456;              // 131072
  float* knew     = q + 131072;                // 32768
  float* vnew     = knew + 32768;              // 32768
  float* attn_out = vnew + 32768;              // 131072
  float* pvp      = attn_out + 131072;         // 32*256*4*128 = 4,194,304
  float* msp      = pvp + 4194304;             // 65536
  float* partE    = msp + 65536;               // 32*32*4096 = 4,194,304
  float* out      = (float*)d_out;

  k_gemm<QKV_N><<<24 * 2 * SLICES, 256, 0, stream>>>(x, wqkv, partA, 24);
  k_rope<<<384, 256, 0, stream>>>(partA, cosv, sinv, q, knew, vnew);
  k_attn<<<(256 * NCW) / 4, 256, 0, stream>>>(q, knew, vnew, cache_k, cache_v,
                                              mask, start_p, pvp, msp);
  k_combine<<<512, 256, 0, stream>>>(pvp, msp, attn_out);
  k_gemm<DIM><<<16 * 2 * SLICES, 256, 0, stream>>>(attn_out, wo, partE, 16);
  k_reduce<<<512, 256, 0, stream>>>(partE, out);
}

// Round 12
// 315.306 us; speedup vs baseline: 1.0297x; 1.0297x over previous
//
#include <hip/hip_runtime.h>
#include <math.h>

#define DIM 4096
#define NH 32
#define NKV 8
#define HD 128
#define WINDOW 4096
#define BATCH 32
#define QKV_N 6144
#define ATTN_SCALE 0.08838834764831845f
#define WCHUNK 256
#define NCW 16         // WINDOW / WCHUNK
#define SLICES 32      // GEMM K-split, kn = 128

__device__ __forceinline__ float4 f4max(float4 a, float4 b) {
  return make_float4(fmaxf(a.x, b.x), fmaxf(a.y, b.y), fmaxf(a.z, b.z), fmaxf(a.w, b.w));
}
__device__ __forceinline__ float4 f4add(float4 a, float4 b) {
  return make_float4(a.x + b.x, a.y + b.y, a.z + b.z, a.w + b.w);
}
__device__ __forceinline__ void fma4(float4& a, float4 x, float4 y) {
  a.x = fmaf(x.x, y.x, a.x); a.y = fmaf(x.y, y.y, a.y);
  a.z = fmaf(x.z, y.z, a.z); a.w = fmaf(x.w, y.w, a.w);
}
__device__ __forceinline__ void fma4s(float4& a, float s, float4 v) {
  a.x = fmaf(s, v.x, a.x); a.y = fmaf(s, v.y, a.y);
  a.z = fmaf(s, v.z, a.z); a.w = fmaf(s, v.w, a.w);
}
__device__ __forceinline__ float4 wred_max(float4 v) {
#pragma unroll
  for (int o = 1; o < 64; o <<= 1) {
    v.x = fmaxf(v.x, __shfl_xor(v.x, o));
    v.y = fmaxf(v.y, __shfl_xor(v.y, o));
    v.z = fmaxf(v.z, __shfl_xor(v.z, o));
    v.w = fmaxf(v.w, __shfl_xor(v.w, o));
  }
  return v;
}
__device__ __forceinline__ float4 wred_add(float4 v) {
#pragma unroll
  for (int o = 1; o < 64; o <<= 1) {
    v.x += __shfl_xor(v.x, o);
    v.y += __shfl_xor(v.y, o);
    v.z += __shfl_xor(v.z, o);
    v.w += __shfl_xor(v.w, o);
  }
  return v;
}

// ---------------------------------------------------------------------------
// GEMM partials v3 (round-9 proven best): wave tile = 256 cols x 4 rows x 128 k.
// blockIdx = strip (fastest) + rowhalf*nstrip + slice*2*nstrip; row-half pairs
// sit nstrip (=0 mod 8) apart -> same XCD L2 serves the shared w-tile.
// Lane l -> 4 consecutive cols: each wave w-load = 1 KB contiguous unique.
// part[(slice*32 + r)*N + c] = sum_{k in slice} x[r][k] * w[k][c]
// ---------------------------------------------------------------------------
template<int N>
__global__ __launch_bounds__(256, 4)
void k_gemm(const float* __restrict__ x, const float* __restrict__ w,
            float* __restrict__ part, int nstrip) {
  const int bid = blockIdx.x;
  const int strip = bid % nstrip;
  const int rh = (bid / nstrip) & 1;
  const int slice = bid / (nstrip * 2);
  const int t = threadIdx.x;
  const int l = t & 63;
  const int r0 = rh * 16 + (t >> 6) * 4;   // 4 rows per thread
  const int ks = slice * 128;
  const int c0 = strip * 256;

  float4 acc[4];
#pragma unroll
  for (int i = 0; i < 4; ++i) acc[i] = make_float4(0.f, 0.f, 0.f, 0.f);

  const float* wp = w + (size_t)ks * N + c0 + 4 * l;
  const float* xp = x + (size_t)r0 * DIM + ks;

  for (int k4 = 0; k4 < 32; ++k4) {
    float4 xr[4];
#pragma unroll
    for (int r = 0; r < 4; ++r)
      xr[r] = *(const float4*)(xp + (size_t)r * DIM + 4 * k4);
#pragma unroll
    for (int kk = 0; kk < 4; ++kk) {
      float4 wv = *(const float4*)wp;
      wp += N;
#pragma unroll
      for (int r = 0; r < 4; ++r) {
        float xs = (kk == 0) ? xr[r].x : (kk == 1) ? xr[r].y : (kk == 2) ? xr[r].z : xr[r].w;
        fma4s(acc[r], xs, wv);
      }
    }
  }
  float* p = part + ((size_t)slice * 32 + r0) * N + c0 + 4 * l;
#pragma unroll
  for (int i = 0; i < 4; ++i) *(float4*)(p + (size_t)i * N) = acc[i];
}

// ---------------------------------------------------------------------------
// Slice-reduce qkv partials + RoPE, scatter q / knew / vnew.
// ---------------------------------------------------------------------------
__global__ __launch_bounds__(256)
void k_rope(const float* __restrict__ part, const float* __restrict__ cosv,
            const float* __restrict__ sinv, float* __restrict__ q,
            float* __restrict__ knew, float* __restrict__ vnew) {
  int idx = blockIdx.x * 256 + threadIdx.x;   // < 32*48*64 = 98304
  int r = idx / 3072;
  int rem = idx - r * 3072;
  int head = rem >> 6;
  int d = rem & 63;
  int c1 = head * 128 + d;
  int c2 = c1 + 64;
  float v1 = 0.f, v2 = 0.f;
#pragma unroll 8
  for (int s = 0; s < SLICES; ++s) {
    v1 += part[((size_t)s * 32 + r) * QKV_N + c1];
    v2 += part[((size_t)s * 32 + r) * QKV_N + c2];
  }
  if (head < NH + NKV) {
    float c_lo = cosv[d], c_hi = cosv[d + 64];
    float s_lo = sinv[d], s_hi = sinv[d + 64];
    float o1 = v1 * c_lo - v2 * s_lo;
    float o2 = v2 * c_hi + v1 * s_hi;
    if (head < NH) {
      q[((size_t)r * NH + head) * HD + d] = o1;
      q[((size_t)r * NH + head) * HD + d + 64] = o2;
    } else {
      int g = head - NH;
      knew[((size_t)r * NKV + g) * HD + d] = o1;
      knew[((size_t)r * NKV + g) * HD + d + 64] = o2;
    }
  } else {
    int g = head - NH - NKV;
    vnew[((size_t)r * NKV + g) * HD + d] = v1;
    vnew[((size_t)r * NKV + g) * HD + d + 64] = v2;
  }
}

// ---------------------------------------------------------------------------
// Flash-decode: each wave owns one 256-position chunk of one (b,g).
// grid 1024 x 256thr (4 waves). Wave-private LDS, no __syncthreads.
// (Round-9 proven best: 315.6 us total.)
// ---------------------------------------------------------------------------
__global__ __launch_bounds__(256, 4)
void k_attn(const float* __restrict__ q, const float* __restrict__ knew,
            const float* __restrict__ vnew, const float* __restrict__ cache_k,
            const float* __restrict__ cache_v, const float* __restrict__ mask,
            const int* __restrict__ start_pos_p,
            float* __restrict__ pvp, float* __restrict__ msp) {
  __shared__ __align__(16) float q_s_all[4][4 * HD];        // 8 KB
  __shared__ __align__(16) float s_s_all[4][WCHUNK * 4];    // 16 KB
  const int t = threadIdx.x;
  const int w = t >> 6, lane = t & 63;
  float* q_s = q_s_all[w];
  float* s_s = s_s_all[w];
  const int gw = blockIdx.x * 4 + w;    // 0..4095
  const int bg = gw & 255;
  const int c = gw >> 8;                // 0..15
  const int b = bg >> 3;
  const int sp = start_pos_p[0];
  const int cur = sp & (WINDOW - 1);
  int plen = ((sp + 1 + 31) >> 5) << 5;
  if (plen > WINDOW) plen = WINDOW;
  const int t0 = c * WCHUNK;
  const int tend = min(t0 + WCHUNK, plen);

  const size_t pidx = ((size_t)c * 256 + bg) * 4;
  float* pvb = pvp + pidx * HD;
  float* msb = msp + pidx * 2;

  if (t0 >= plen) {
    if (lane < 8) msb[lane] = (lane & 1) ? 0.f : -1e30f;
    for (int i = lane; i < 4 * HD; i += 64) pvb[i] = 0.f;
    return;
  }

  // wave-local q load (4 heads x 128 contiguous)
  {
    const float* qsrc = q + ((size_t)b * NH + (bg & 7) * 4) * HD;
    *(float4*)(&q_s[lane * 8]) = *(const float4*)(qsrc + lane * 8);
    *(float4*)(&q_s[lane * 8 + 4]) = *(const float4*)(qsrc + lane * 8 + 4);
  }

  const float* kbase = cache_k + (size_t)bg * WINDOW * HD;
  const float* vbase = cache_v + (size_t)bg * WINDOW * HD;
  const float* krow_new = knew + (size_t)bg * HD;
  const float* vrow_new = vnew + (size_t)bg * HD;

  // ---- Phase 1: scores; 16 row-lanes x 16 iters; batch 8 loads/row ----
  {
    const int p0 = lane >> 2;   // 0..15
    const int dl = lane & 3;
    for (int tt = t0 + p0; tt < t0 + WCHUNK; tt += 16) {
      if (tt < tend) {
        const float* krow = (tt == cur) ? krow_new : (kbase + (size_t)tt * HD);
        float4 kreg[8];
#pragma unroll
        for (int j = 0; j < 8; ++j)
          kreg[j] = *(const float4*)(krow + 4 * (dl + 4 * j));
        float4 a0 = {0,0,0,0}, a1 = {0,0,0,0}, a2 = {0,0,0,0}, a3 = {0,0,0,0};
#pragma unroll
        for (int j = 0; j < 8; ++j) {
          const int f = dl + 4 * j;
          fma4(a0, kreg[j], *(const float4*)(&q_s[0 * HD + 4 * f]));
          fma4(a1, kreg[j], *(const float4*)(&q_s[1 * HD + 4 * f]));
          fma4(a2, kreg[j], *(const float4*)(&q_s[2 * HD + 4 * f]));
          fma4(a3, kreg[j], *(const float4*)(&q_s[3 * HD + 4 * f]));
        }
        float s0 = a0.x + a0.y + a0.z + a0.w;
        float s1 = a1.x + a1.y + a1.z + a1.w;
        float s2 = a2.x + a2.y + a2.z + a2.w;
        float s3 = a3.x + a3.y + a3.z + a3.w;
        s0 += __shfl_xor(s0, 1); s0 += __shfl_xor(s0, 2);
        s1 += __shfl_xor(s1, 1); s1 += __shfl_xor(s1, 2);
        s2 += __shfl_xor(s2, 1); s2 += __shfl_xor(s2, 2);
        s3 += __shfl_xor(s3, 1); s3 += __shfl_xor(s3, 2);
        float sv = (dl == 0) ? s0 : (dl == 1) ? s1 : (dl == 2) ? s2 : s3;
        s_s[(tt - t0) * 4 + dl] = sv * ATTN_SCALE + mask[(size_t)b * WINDOW + tt];
      } else {
        s_s[(tt - t0) * 4 + dl] = -1e30f;
      }
    }
  }

  // ---- Phase 2: wave softmax over 256 rows (4 rows/lane) ----
  float4 r0v = *(const float4*)(&s_s[(lane +   0) * 4]);
  float4 r1v = *(const float4*)(&s_s[(lane +  64) * 4]);
  float4 r2v = *(const float4*)(&s_s[(lane + 128) * 4]);
  float4 r3v = *(const float4*)(&s_s[(lane + 192) * 4]);
  float4 mx = wred_max(f4max(f4max(r0v, r1v), f4max(r2v, r3v)));
  float4 e0, e1, e2, e3;
  e0.x = __expf(r0v.x - mx.x); e0.y = __expf(r0v.y - mx.y);
  e0.z = __expf(r0v.z - mx.z); e0.w = __expf(r0v.w - mx.w);
  e1.x = __expf(r1v.x - mx.x); e1.y = __expf(r1v.y - mx.y);
  e1.z = __expf(r1v.z - mx.z); e1.w = __expf(r1v.w - mx.w);
  e2.x = __expf(r2v.x - mx.x); e2.y = __expf(r2v.y - mx.y);
  e2.z = __expf(r2v.z - mx.z); e2.w = __expf(r2v.w - mx.w);
  e3.x = __expf(r3v.x - mx.x); e3.y = __expf(r3v.y - mx.y);
  e3.z = __expf(r3v.z - mx.z); e3.w = __expf(r3v.w - mx.w);
  *(float4*)(&s_s[(lane +   0) * 4]) = e0;
  *(float4*)(&s_s[(lane +  64) * 4]) = e1;
  *(float4*)(&s_s[(lane + 128) * 4]) = e2;
  *(float4*)(&s_s[(lane + 192) * 4]) = e3;
  float4 sm = wred_add(f4add(f4add(e0, e1), f4add(e2, e3)));
  if (lane == 0) {
    msb[0] = mx.x; msb[1] = sm.x;
    msb[2] = mx.y; msb[3] = sm.y;
    msb[4] = mx.z; msb[5] = sm.z;
    msb[6] = mx.w; msb[7] = sm.w;
  }

  // ---- Phase 3: PV; half-wave owns even/odd rows; unroll for MLP ----
  {
    const int d4 = lane & 31;
    const int half = lane >> 5;
    float4 a0 = {0,0,0,0}, a1 = {0,0,0,0}, a2 = {0,0,0,0}, a3 = {0,0,0,0};
#pragma unroll 4
    for (int tt = t0 + half; tt < tend; tt += 2) {
      const float* vrow = (tt == cur) ? vrow_new : (vbase + (size_t)tt * HD);
      float4 vv = *(const float4*)(vrow + 4 * d4);
      float4 p = *(const float4*)(&s_s[(tt - t0) * 4]);
      fma4s(a0, p.x, vv);
      fma4s(a1, p.y, vv);
      fma4s(a2, p.z, vv);
      fma4s(a3, p.w, vv);
    }
    a0.x += __shfl_xor(a0.x, 32); a0.y += __shfl_xor(a0.y, 32);
    a0.z += __shfl_xor(a0.z, 32); a0.w += __shfl_xor(a0.w, 32);
    a1.x += __shfl_xor(a1.x, 32); a1.y += __shfl_xor(a1.y, 32);
    a1.z += __shfl_xor(a1.z, 32); a1.w += __shfl_xor(a1.w, 32);
    a2.x += __shfl_xor(a2.x, 32); a2.y += __shfl_xor(a2.y, 32);
    a2.z += __shfl_xor(a2.z, 32); a2.w += __shfl_xor(a2.w, 32);
    a3.x += __shfl_xor(a3.x, 32); a3.y += __shfl_xor(a3.y, 32);
    a3.z += __shfl_xor(a3.z, 32); a3.w += __shfl_xor(a3.w, 32);
    if (half == 0) {
      *(float4*)(&pvb[0 * HD + 4 * d4]) = a0;
      *(float4*)(&pvb[1 * HD + 4 * d4]) = a1;
      *(float4*)(&pvb[2 * HD + 4 * d4]) = a2;
      *(float4*)(&pvb[3 * HD + 4 * d4]) = a3;
    }
  }
}

// ---------------------------------------------------------------------------
// Combine chunk partials: online LSE merge over NCW chunks.
// ---------------------------------------------------------------------------
__global__ __launch_bounds__(256)
void k_combine(const float* __restrict__ pvp, const float* __restrict__ msp,
               float* __restrict__ attn_out) {
  int idx = blockIdx.x * 256 + threadIdx.x;   // < 32*4096
  int b = idx >> 12;
  int rem = idx & 4095;
  int hf = rem >> 7;
  int d = rem & 127;
  int g = hf >> 2, hh = hf & 3;
  int bg = b * 8 + g;
  float M = -1e30f, den = 0.f, num = 0.f;
#pragma unroll 4
  for (int c = 0; c < NCW; ++c) {
    size_t base = ((size_t)c * 256 + bg) * 4 + hh;
    float m = msp[base * 2];
    float s = msp[base * 2 + 1];
    float p = pvp[base * HD + d];
    float Mn = fmaxf(M, m);
    float so = __expf(M - Mn);
    float sn = __expf(m - Mn);
    den = den * so + s * sn;
    num = num * so + p * sn;
    M = Mn;
  }
  attn_out[idx] = num / den;
}

// ---------------------------------------------------------------------------
// Reduce wo partials -> out.
// ---------------------------------------------------------------------------
__global__ __launch_bounds__(256)
void k_reduce(const float* __restrict__ part, float* __restrict__ out) {
  int idx = blockIdx.x * 256 + threadIdx.x;   // < 32*4096
  float s = 0.f;
#pragma unroll 8
  for (int sl = 0; sl < SLICES; ++sl) s += part[(size_t)sl * BATCH * DIM + idx];
  out[idx] = s;
}

extern "C" void kernel_launch(void* const* d_in, const int* in_sizes, int n_in,
                              void* d_out, int out_size, void* d_ws, size_t ws_size,
                              hipStream_t stream) {
  const float* x       = (const float*)d_in[0];
  const float* wqkv    = (const float*)d_in[1];
  const float* wo      = (const float*)d_in[2];
  const float* cosv    = (const float*)d_in[3];
  const float* sinv    = (const float*)d_in[4];
  const float* cache_k = (const float*)d_in[5];
  const float* cache_v = (const float*)d_in[6];
  const float* mask    = (const float*)d_in[7];
  const int*   start_p = (const int*)d_in[8];
  float* ws = (float*)d_ws;

  float* partA    = ws;                        // 32*32*6144 = 6,291,456
  float* q        = ws + 6291456;              // 131072
  float* knew     = q + 131072;                // 32768
  float* vnew     = knew + 32768;              // 32768
  float* attn_out = vnew + 32768;              // 131072
  float* pvp      = attn_out + 131072;         // 16*256*4*128 = 2,097,152
  float* msp      = pvp + 2097152;             // 16384
  float* partE    = msp + 16384;               // 32*32*4096 = 4,194,304
  float* out      = (float*)d_out;

  k_gemm<QKV_N><<<24 * 2 * SLICES, 256, 0, stream>>>(x, wqkv, partA, 24);
  k_rope<<<384, 256, 0, stream>>>(partA, cosv, sinv, q, knew, vnew);
  k_attn<<<(256 * NCW) / 4, 256, 0, stream>>>(q, knew, vnew, cache_k, cache_v,
                                              mask, start_p, pvp, msp);
  k_combine<<<512, 256, 0, stream>>>(pvp, msp, attn_out);
  k_gemm<DIM><<<16 * 2 * SLICES, 256, 0, stream>>>(attn_out, wo, partE, 16);
  k_reduce<<<512, 256, 0, stream>>>(partE, out);
}